// Round 1
// baseline (541.679 us; speedup 1.0000x reference)
//
#include <hip/hip_runtime.h>

#define DEV __device__ __forceinline__

using u16 = unsigned short;
typedef __attribute__((ext_vector_type(8))) short    short8;   // 8 bf16 (4 VGPRs) MFMA frag
typedef __attribute__((ext_vector_type(8))) u16      ushort8;
typedef __attribute__((ext_vector_type(4))) float    f32x4;

// ---------- problem constants ----------
constexpr int BB = 4;          // batch
constexpr int TT = 2048;       // seq len
constexpr int CC = 1024;       // embed dim
constexpr int HH = 16;         // heads
constexpr int DD = 64;         // head dim
constexpr int MM = BB * TT;    // 8192 rows
constexpr int N1 = 3 * CC;     // 3072 (qkv)

// fp32 -> bf16 round-to-nearest-even
DEV u16 f2bf(float f) {
    unsigned u = __float_as_uint(f);
    unsigned r = (u + 0x7FFFu + ((u >> 16) & 1u)) >> 16;
    return (u16)r;
}

DEV void gload_lds16(const void* g, void* l) {
    __builtin_amdgcn_global_load_lds((const __attribute__((address_space(1))) void*)g,
                                     (__attribute__((address_space(3))) void*)l,
                                     16, 0, 0);
}

// ---------- converters ----------
__global__ void k_cvt_x(const float* __restrict__ src, u16* __restrict__ dst) {
    int i = (blockIdx.x * 256 + threadIdx.x) * 8;   // total 8,388,608 elems
    f32x4 a = *(const f32x4*)(src + i);
    f32x4 b = *(const f32x4*)(src + i + 4);
    ushort8 u;
    u[0] = f2bf(a[0]); u[1] = f2bf(a[1]); u[2] = f2bf(a[2]); u[3] = f2bf(a[3]);
    u[4] = f2bf(b[0]); u[5] = f2bf(b[1]); u[6] = f2bf(b[2]); u[7] = f2bf(b[3]);
    *(ushort8*)(dst + i) = u;
}

// dst[n][k] = bf16(src[k][n]);  src: [Kd][Nd], dst: [Nd][Kd]
__global__ void k_transpose_cvt(const float* __restrict__ src, u16* __restrict__ dst,
                                int Kd, int Nd) {
    size_t o = ((size_t)blockIdx.x * 256 + threadIdx.x) * 8;
    int n  = (int)(o / Kd);
    int k0 = (int)(o % Kd);
    ushort8 u;
#pragma unroll
    for (int i = 0; i < 8; ++i)
        u[i] = f2bf(src[(size_t)(k0 + i) * Nd + n]);
    *(ushort8*)(dst + o) = u;
}

// ---------- shared 128x128 GEMM mainloop (m97 structure) ----------
// A: [*,1024] bf16 row-major (pre-offset to tile row base)
// B: [*,1024] bf16 row-major = B^T layout (pre-offset to tile col base)
DEV void gemm_mainloop(const u16* __restrict__ Ag, const u16* __restrict__ Bg,
                       u16* As, u16* Bs, f32x4 acc[4][4]) {
    const int tid = threadIdx.x, lane = tid & 63, wid = tid >> 6;
    const int wr = wid >> 1, wc = wid & 1;
#pragma unroll 1
    for (int kt = 0; kt < 1024; kt += 32) {
        __syncthreads();
#pragma unroll
        for (int p = 0; p < 2; ++p) {
            int cb = p * 256 + wid * 64;
            int chunk = cb + lane;
            int row = chunk >> 2, kc = chunk & 3;
            gload_lds16(Ag + (size_t)row * 1024 + kt + kc * 8, As + cb * 8);
            gload_lds16(Bg + (size_t)row * 1024 + kt + kc * 8, Bs + cb * 8);
        }
        __syncthreads();
        short8 aF[4], bF[4];
#pragma unroll
        for (int m = 0; m < 4; ++m)
            aF[m] = *(const short8*)&As[(wr * 64 + m * 16 + (lane & 15)) * 32 + (lane >> 4) * 8];
#pragma unroll
        for (int n = 0; n < 4; ++n)
            bF[n] = *(const short8*)&Bs[(wc * 64 + n * 16 + (lane & 15)) * 32 + (lane >> 4) * 8];
#pragma unroll
        for (int m = 0; m < 4; ++m)
#pragma unroll
            for (int n = 0; n < 4; ++n)
                acc[m][n] = __builtin_amdgcn_mfma_f32_16x16x32_bf16(aF[m], bF[n], acc[m][n], 0, 0, 0);
    }
}

// GEMM1: qkv = x @ W_qkv + b; scatter to q/k/v [B*H][T][D] bf16
__global__ __launch_bounds__(256) void k_gemm_qkv(const u16* __restrict__ xb,
                                                  const u16* __restrict__ wt,
                                                  const float* __restrict__ bqkv,
                                                  u16* __restrict__ qb,
                                                  u16* __restrict__ kb,
                                                  u16* __restrict__ vb) {
    __shared__ u16 As[4096], Bs[4096];
    f32x4 acc[4][4];
#pragma unroll
    for (int m = 0; m < 4; ++m)
#pragma unroll
        for (int n = 0; n < 4; ++n) acc[m][n] = (f32x4){0.f, 0.f, 0.f, 0.f};
    const int rowBase = blockIdx.x * 128, colBase = blockIdx.y * 128;
    gemm_mainloop(xb + (size_t)rowBase * 1024, wt + (size_t)colBase * 1024, As, Bs, acc);
    const int lane = threadIdx.x & 63, wid = threadIdx.x >> 6;
    const int wr = wid >> 1, wc = wid & 1;
#pragma unroll
    for (int n = 0; n < 4; ++n) {
        int gn = colBase + wc * 64 + n * 16 + (lane & 15);
        float bias = bqkv[gn];
        int which = gn >> 10, cc = gn & 1023, h = cc >> 6, d = cc & 63;
        u16* dst = which == 0 ? qb : (which == 1 ? kb : vb);
#pragma unroll
        for (int m = 0; m < 4; ++m) {
#pragma unroll
            for (int r = 0; r < 4; ++r) {
                int gm = rowBase + wr * 64 + m * 16 + (lane >> 4) * 4 + r;
                int b = gm >> 11, t = gm & 2047;
                dst[(((size_t)b * HH + h) * TT + t) * DD + d] = f2bf(acc[m][n][r] + bias);
            }
        }
    }
}

// GEMM2: out = o @ W_proj + b; fp32 output
__global__ __launch_bounds__(256) void k_gemm_proj(const u16* __restrict__ ob,
                                                   const u16* __restrict__ wt,
                                                   const float* __restrict__ bproj,
                                                   float* __restrict__ out) {
    __shared__ u16 As[4096], Bs[4096];
    f32x4 acc[4][4];
#pragma unroll
    for (int m = 0; m < 4; ++m)
#pragma unroll
        for (int n = 0; n < 4; ++n) acc[m][n] = (f32x4){0.f, 0.f, 0.f, 0.f};
    const int rowBase = blockIdx.x * 128, colBase = blockIdx.y * 128;
    gemm_mainloop(ob + (size_t)rowBase * 1024, wt + (size_t)colBase * 1024, As, Bs, acc);
    const int lane = threadIdx.x & 63, wid = threadIdx.x >> 6;
    const int wr = wid >> 1, wc = wid & 1;
#pragma unroll
    for (int n = 0; n < 4; ++n) {
        int gn = colBase + wc * 64 + n * 16 + (lane & 15);
        float bias = bproj[gn];
#pragma unroll
        for (int m = 0; m < 4; ++m) {
#pragma unroll
            for (int r = 0; r < 4; ++r) {
                int gm = rowBase + wr * 64 + m * 16 + (lane >> 4) * 4 + r;
                out[(size_t)gm * 1024 + gn] = acc[m][n][r] + bias;
            }
        }
    }
}

// ---------- causal flash attention ----------
// q/k/v: [B*H][T][D] bf16.  o: [B*T][C] bf16.
// block = (qi, bh): 64 Q rows, 4 waves x 16 rows; KV tiles of 64.
__global__ __launch_bounds__(256) void k_attn(const u16* __restrict__ qb,
                                              const u16* __restrict__ kb,
                                              const u16* __restrict__ vb,
                                              u16* __restrict__ ob) {
    __shared__ u16 Kt[64 * 64];     // [key][d], XOR-swizzled
    __shared__ u16 Vt[64 * 64];     // [d][key], XOR-swizzled
    __shared__ u16 Pl[4][16 * 64];  // per-wave P, XOR-swizzled

    const int tid = threadIdx.x, lane = tid & 63, wid = tid >> 6;
    const int qi = blockIdx.x, bh = blockIdx.y;
    const size_t base = (size_t)bh * TT * DD;

    // Q fragments: rows qi*64 + wid*16 + (lane&15), k = d
    short8 aQ[2];
    {
        int qrow = qi * 64 + wid * 16 + (lane & 15);
#pragma unroll
        for (int ks = 0; ks < 2; ++ks)
            aQ[ks] = *(const short8*)(qb + base + (size_t)qrow * DD + ks * 32 + (lane >> 4) * 8);
    }

    float mrun[4], lrun[4];
    f32x4 oacc[4];
#pragma unroll
    for (int r = 0; r < 4; ++r) { mrun[r] = -1e30f; lrun[r] = 0.f; }
#pragma unroll
    for (int dt = 0; dt < 4; ++dt) oacc[dt] = (f32x4){0.f, 0.f, 0.f, 0.f};

    for (int j = 0; j <= qi; ++j) {
        __syncthreads();
        // stage K tile and transposed V tile (XOR-swizzled rows of 128B)
#pragma unroll
        for (int p = 0; p < 2; ++p) {
            int chunk = p * 256 + tid;
            int row = chunk >> 3, dc = chunk & 7;
            ushort8 k8 = *(const ushort8*)(kb + base + (size_t)(j * 64 + row) * DD + dc * 8);
            *(ushort8*)&Kt[(row * 64 + dc * 8) ^ ((row & 7) << 3)] = k8;
            ushort8 v8 = *(const ushort8*)(vb + base + (size_t)(j * 64 + row) * DD + dc * 8);
#pragma unroll
            for (int ii = 0; ii < 8; ++ii) {
                int d = dc * 8 + ii;
                Vt[(d * 64 + row) ^ ((d & 7) << 3)] = v8[ii];
            }
        }
        __syncthreads();

        // S = Q K^T  (per wave: 16 rows x 64 keys)
        f32x4 sacc[4];
#pragma unroll
        for (int ct = 0; ct < 4; ++ct) sacc[ct] = (f32x4){0.f, 0.f, 0.f, 0.f};
#pragma unroll
        for (int ct = 0; ct < 4; ++ct) {
            int key = ct * 16 + (lane & 15);
#pragma unroll
            for (int ks = 0; ks < 2; ++ks) {
                short8 bK = *(const short8*)&Kt[(key * 64 + ks * 32 + (lane >> 4) * 8) ^ ((key & 7) << 3)];
                sacc[ct] = __builtin_amdgcn_mfma_f32_16x16x32_bf16(aQ[ks], bK, sacc[ct], 0, 0, 0);
            }
        }

        // scale + causal mask + online softmax
        float rowmax[4] = {-1e30f, -1e30f, -1e30f, -1e30f};
#pragma unroll
        for (int ct = 0; ct < 4; ++ct) {
#pragma unroll
            for (int r = 0; r < 4; ++r) {
                float s = sacc[ct][r] * 0.125f;
                if (j == qi && (ct * 16 + (lane & 15)) > (wid * 16 + (lane >> 4) * 4 + r))
                    s = -1e30f;
                sacc[ct][r] = s;
                rowmax[r] = fmaxf(rowmax[r], s);
            }
        }
#pragma unroll
        for (int off = 1; off < 16; off <<= 1)
#pragma unroll
            for (int r = 0; r < 4; ++r)
                rowmax[r] = fmaxf(rowmax[r], __shfl_xor(rowmax[r], off));
        float fscale[4], rsum[4];
#pragma unroll
        for (int r = 0; r < 4; ++r) {
            float mnew = fmaxf(mrun[r], rowmax[r]);
            fscale[r] = __expf(mrun[r] - mnew);
            mrun[r] = mnew;
            rsum[r] = 0.f;
        }
#pragma unroll
        for (int ct = 0; ct < 4; ++ct)
#pragma unroll
            for (int r = 0; r < 4; ++r) {
                float p = __expf(sacc[ct][r] - mrun[r]);
                sacc[ct][r] = p;
                rsum[r] += p;
            }
#pragma unroll
        for (int off = 1; off < 16; off <<= 1)
#pragma unroll
            for (int r = 0; r < 4; ++r)
                rsum[r] += __shfl_xor(rsum[r], off);
#pragma unroll
        for (int r = 0; r < 4; ++r) lrun[r] = lrun[r] * fscale[r] + rsum[r];
#pragma unroll
        for (int dt = 0; dt < 4; ++dt)
#pragma unroll
            for (int r = 0; r < 4; ++r) oacc[dt][r] *= fscale[r];

        // write P (bf16) to per-wave LDS, swizzled
#pragma unroll
        for (int ct = 0; ct < 4; ++ct)
#pragma unroll
            for (int r = 0; r < 4; ++r) {
                int row = (lane >> 4) * 4 + r, col = ct * 16 + (lane & 15);
                Pl[wid][(row * 64 + col) ^ ((row & 7) << 3)] = f2bf(sacc[ct][r]);
            }

        // O += P V  (A = P [qrow][key], B = Vt[d][key])
        short8 aP[2];
        {
            int prow = lane & 15;
#pragma unroll
            for (int ks = 0; ks < 2; ++ks)
                aP[ks] = *(const short8*)&Pl[wid][(prow * 64 + ks * 32 + (lane >> 4) * 8) ^ ((prow & 7) << 3)];
        }
#pragma unroll
        for (int dt = 0; dt < 4; ++dt) {
            int d = dt * 16 + (lane & 15);
#pragma unroll
            for (int ks = 0; ks < 2; ++ks) {
                short8 bV = *(const short8*)&Vt[(d * 64 + ks * 32 + (lane >> 4) * 8) ^ ((d & 7) << 3)];
                oacc[dt] = __builtin_amdgcn_mfma_f32_16x16x32_bf16(aP[ks], bV, oacc[dt], 0, 0, 0);
            }
        }
    }

    // epilogue: O /= l, write [B*T][C] bf16
    const int b = bh >> 4, h = bh & 15;
#pragma unroll
    for (int dt = 0; dt < 4; ++dt)
#pragma unroll
        for (int r = 0; r < 4; ++r) {
            int t = qi * 64 + wid * 16 + (lane >> 4) * 4 + r;
            float v = oacc[dt][r] * (1.f / lrun[r]);
            ob[((size_t)(b * TT + t)) * CC + h * 64 + dt * 16 + (lane & 15)] = f2bf(v);
        }
}

// ---------- launch ----------
extern "C" void kernel_launch(void* const* d_in, const int* in_sizes, int n_in,
                              void* d_out, int out_size, void* d_ws, size_t ws_size,
                              hipStream_t stream) {
    const float* x     = (const float*)d_in[0];
    const float* Wqkv  = (const float*)d_in[1];
    const float* bqkv  = (const float*)d_in[2];
    const float* Wproj = (const float*)d_in[3];
    const float* bproj = (const float*)d_in[4];
    float* out = (float*)d_out;

    char* ws = (char*)d_ws;
    u16* xb    = (u16*)(ws + 0);          // 16,777,216 B  (reused as ob after GEMM1)
    u16* wqkvT = (u16*)(ws + 16777216);   //  6,291,456 B
    u16* wprojT= (u16*)(ws + 23068672);   //  2,097,152 B
    u16* qb    = (u16*)(ws + 25165824);   // 16,777,216 B
    u16* kb    = (u16*)(ws + 41943040);   // 16,777,216 B
    u16* vb    = (u16*)(ws + 58720256);   // 16,777,216 B  (total 75,497,472 B)
    u16* ob    = xb;                      // alias: x dead after GEMM1

    k_cvt_x<<<dim3(MM * CC / (256 * 8)), 256, 0, stream>>>(x, xb);
    k_transpose_cvt<<<dim3(N1 * CC / (256 * 8)), 256, 0, stream>>>(Wqkv, wqkvT, CC, N1);
    k_transpose_cvt<<<dim3(CC * CC / (256 * 8)), 256, 0, stream>>>(Wproj, wprojT, CC, CC);
    k_gemm_qkv<<<dim3(MM / 128, N1 / 128), 256, 0, stream>>>(xb, wqkvT, bqkv, qb, kb, vb);
    k_attn<<<dim3(TT / 64, BB * HH), 256, 0, stream>>>(qb, kb, vb, ob);
    k_gemm_proj<<<dim3(MM / 128, CC / 128), 256, 0, stream>>>(ob, wprojT, bproj, out);
}

// Round 2
// 309.538 us; speedup vs baseline: 1.7500x; 1.7500x over previous
//
#include <hip/hip_runtime.h>

#define DEV __device__ __forceinline__

using u16 = unsigned short;
using u32 = unsigned int;
typedef __attribute__((ext_vector_type(8)))  short  short8;   // 8 bf16 (4 VGPRs) MFMA frag
typedef __attribute__((ext_vector_type(8)))  u16    ushort8;
typedef __attribute__((ext_vector_type(4)))  float  f32x4;
typedef __attribute__((ext_vector_type(16))) float  f32x16;

// ---------- problem constants ----------
constexpr int BB = 4;          // batch
constexpr int TT = 2048;       // seq len
constexpr int CC = 1024;       // embed dim
constexpr int HH = 16;         // heads
constexpr int DD = 64;         // head dim
constexpr int MM = BB * TT;    // 8192 rows
constexpr int N1 = 3 * CC;     // 3072 (qkv)

// fp32 -> bf16 round-to-nearest-even
DEV u16 f2bf(float f) {
    unsigned u = __float_as_uint(f);
    unsigned r = (u + 0x7FFFu + ((u >> 16) & 1u)) >> 16;
    return (u16)r;
}

DEV u32 cvtpk(float lo, float hi) {
    u32 r;
    asm("v_cvt_pk_bf16_f32 %0, %1, %2" : "=v"(r) : "v"(lo), "v"(hi));
    return r;
}

DEV void gload_lds16(const void* g, void* l) {
    __builtin_amdgcn_global_load_lds((const __attribute__((address_space(1))) void*)g,
                                     (__attribute__((address_space(3))) void*)l,
                                     16, 0, 0);
}

// ---------- converters ----------
__global__ void k_cvt_x(const float* __restrict__ src, u16* __restrict__ dst) {
    int i = (blockIdx.x * 256 + threadIdx.x) * 8;
    f32x4 a = *(const f32x4*)(src + i);
    f32x4 b = *(const f32x4*)(src + i + 4);
    ushort8 u;
    u[0] = f2bf(a[0]); u[1] = f2bf(a[1]); u[2] = f2bf(a[2]); u[3] = f2bf(a[3]);
    u[4] = f2bf(b[0]); u[5] = f2bf(b[1]); u[6] = f2bf(b[2]); u[7] = f2bf(b[3]);
    *(ushort8*)(dst + i) = u;
}

// dst[n][k] = bf16(src[k][n]);  src: [Kd][Nd], dst: [Nd][Kd]
__global__ void k_transpose_cvt(const float* __restrict__ src, u16* __restrict__ dst,
                                int Kd, int Nd) {
    size_t o = ((size_t)blockIdx.x * 256 + threadIdx.x) * 8;
    int n  = (int)(o / Kd);
    int k0 = (int)(o % Kd);
    ushort8 u;
#pragma unroll
    for (int i = 0; i < 8; ++i)
        u[i] = f2bf(src[(size_t)(k0 + i) * Nd + n]);
    *(ushort8*)(dst + o) = u;
}

// ---------- shared 128x128 GEMM mainloop (m97 structure) ----------
DEV void gemm_mainloop(const u16* __restrict__ Ag, const u16* __restrict__ Bg,
                       u16* As, u16* Bs, f32x4 acc[4][4]) {
    const int tid = threadIdx.x, lane = tid & 63, wid = tid >> 6;
    const int wr = wid >> 1, wc = wid & 1;
#pragma unroll 1
    for (int kt = 0; kt < 1024; kt += 32) {
        __syncthreads();
#pragma unroll
        for (int p = 0; p < 2; ++p) {
            int cb = p * 256 + wid * 64;
            int chunk = cb + lane;
            int row = chunk >> 2, kc = chunk & 3;
            gload_lds16(Ag + (size_t)row * 1024 + kt + kc * 8, As + cb * 8);
            gload_lds16(Bg + (size_t)row * 1024 + kt + kc * 8, Bs + cb * 8);
        }
        __syncthreads();
        short8 aF[4], bF[4];
#pragma unroll
        for (int m = 0; m < 4; ++m)
            aF[m] = *(const short8*)&As[(wr * 64 + m * 16 + (lane & 15)) * 32 + (lane >> 4) * 8];
#pragma unroll
        for (int n = 0; n < 4; ++n)
            bF[n] = *(const short8*)&Bs[(wc * 64 + n * 16 + (lane & 15)) * 32 + (lane >> 4) * 8];
#pragma unroll
        for (int m = 0; m < 4; ++m)
#pragma unroll
            for (int n = 0; n < 4; ++n)
                acc[m][n] = __builtin_amdgcn_mfma_f32_16x16x32_bf16(aF[m], bF[n], acc[m][n], 0, 0, 0);
    }
}

// GEMM1: qkv = x @ W_qkv + b; scatter q (x0.125), k row-major, v TRANSPOSED [bh][d][t]
__global__ __launch_bounds__(256) void k_gemm_qkv(const u16* __restrict__ xb,
                                                  const u16* __restrict__ wt,
                                                  const float* __restrict__ bqkv,
                                                  u16* __restrict__ qb,
                                                  u16* __restrict__ kb,
                                                  u16* __restrict__ vtb) {
    __shared__ u16 As[4096], Bs[4096];
    f32x4 acc[4][4];
#pragma unroll
    for (int m = 0; m < 4; ++m)
#pragma unroll
        for (int n = 0; n < 4; ++n) acc[m][n] = (f32x4){0.f, 0.f, 0.f, 0.f};
    const int rowBase = blockIdx.x * 128, colBase = blockIdx.y * 128;
    gemm_mainloop(xb + (size_t)rowBase * 1024, wt + (size_t)colBase * 1024, As, Bs, acc);
    const int lane = threadIdx.x & 63, wid = threadIdx.x >> 6;
    const int wr = wid >> 1, wc = wid & 1;
#pragma unroll
    for (int n = 0; n < 4; ++n) {
        int gn = colBase + wc * 64 + n * 16 + (lane & 15);
        float bias = bqkv[gn];
        int which = gn >> 10, cc = gn & 1023, hh = cc >> 6, d = cc & 63;
#pragma unroll
        for (int m = 0; m < 4; ++m) {
#pragma unroll
            for (int r = 0; r < 4; ++r) {
                int gm = rowBase + wr * 64 + m * 16 + (lane >> 4) * 4 + r;
                int b = gm >> 11, t = gm & 2047;
                float val = acc[m][n][r] + bias;
                if (which == 0)
                    qb[(((size_t)b * HH + hh) * TT + t) * DD + d] = f2bf(val * 0.125f);
                else if (which == 1)
                    kb[(((size_t)b * HH + hh) * TT + t) * DD + d] = f2bf(val);
                else
                    vtb[(((size_t)b * HH + hh) * DD + d) * TT + t] = f2bf(val);
            }
        }
    }
}

// GEMM2: out = o @ W_proj + b; fp32 output
__global__ __launch_bounds__(256) void k_gemm_proj(const u16* __restrict__ ob,
                                                   const u16* __restrict__ wt,
                                                   const float* __restrict__ bproj,
                                                   float* __restrict__ out) {
    __shared__ u16 As[4096], Bs[4096];
    f32x4 acc[4][4];
#pragma unroll
    for (int m = 0; m < 4; ++m)
#pragma unroll
        for (int n = 0; n < 4; ++n) acc[m][n] = (f32x4){0.f, 0.f, 0.f, 0.f};
    const int rowBase = blockIdx.x * 128, colBase = blockIdx.y * 128;
    gemm_mainloop(ob + (size_t)rowBase * 1024, wt + (size_t)colBase * 1024, As, Bs, acc);
    const int lane = threadIdx.x & 63, wid = threadIdx.x >> 6;
    const int wr = wid >> 1, wc = wid & 1;
#pragma unroll
    for (int n = 0; n < 4; ++n) {
        int gn = colBase + wc * 64 + n * 16 + (lane & 15);
        float bias = bproj[gn];
#pragma unroll
        for (int m = 0; m < 4; ++m) {
#pragma unroll
            for (int r = 0; r < 4; ++r) {
                int gm = rowBase + wr * 64 + m * 16 + (lane >> 4) * 4 + r;
                out[(size_t)gm * 1024 + gn] = acc[m][n][r] + bias;
            }
        }
    }
}

// ---------- causal flash attention, 4 warps x 32 q-rows, KVBLK=64, swapped QK^T ----------
// q,k: [bh][t][64] bf16 (q pre-scaled by 0.125). vt: [bh][64][t] bf16. o: [B*T][C] bf16.
__global__ __launch_bounds__(256) void k_attn2(const u16* __restrict__ qb,
                                               const u16* __restrict__ kb,
                                               const u16* __restrict__ vtb,
                                               u16* __restrict__ ob) {
    __shared__ u16 Kt[2][4096];   // [key 64][d 64], 16B-chunk XOR-swizzled
    __shared__ u16 Vs[2][4096];   // [d 64][key 64], 16B-chunk XOR-swizzled

    const int tid = threadIdx.x, lane = tid & 63, w = tid >> 6;
    const int h = lane >> 5, l31 = lane & 31;
    const int bh = blockIdx.x;
    const int qi = 15 - blockIdx.y;           // heavy blocks dispatched first
    const size_t hb = (size_t)bh * (TT * DD);
    const int qw = qi * 128 + w * 32;         // warp's first q row
    const int nt_blk = 2 * qi + 2;            // KV tiles for the block
    const int nt_w = (qw >> 6) + 1;           // KV tiles this warp computes
    const int cb = tid & ~63;                 // wave-uniform chunk base

    // Q B-frags: col q = qw + l31, k(d) = df*16 + h*8 + j
    short8 qf[4];
#pragma unroll
    for (int df = 0; df < 4; ++df)
        qf[df] = *(const short8*)(qb + hb + (size_t)(qw + l31) * DD + df * 16 + h * 8);

    f32x16 o0, o1;
#pragma unroll
    for (int r = 0; r < 16; ++r) { o0[r] = 0.f; o1[r] = 0.f; }
    float mrun = -1e30f, lrun = 0.f;

    // stage tile 0 into buf 0 (pre-swizzled global source, linear LDS dest)
#pragma unroll
    for (int part = 0; part < 2; ++part) {
        int c = part * 256 + tid;
        int row = c >> 3, sw = (c & 7) ^ (row & 7);
        gload_lds16(kb  + hb + (size_t)row * DD + sw * 8,      &Kt[0][(part * 256 + cb) * 8]);
        gload_lds16(vtb + hb + (size_t)row * TT + sw * 8,      &Vs[0][(part * 256 + cb) * 8]);
    }

    int cur = 0;
    for (int j = 0; j < nt_blk; ++j) {
        asm volatile("s_waitcnt vmcnt(0)" ::: "memory");   // buf[cur] staged
        __syncthreads();                                    // all waves staged; WAR safe
        if (j + 1 < nt_blk) {                               // prefetch next tile (flies under compute)
            const int jb = j + 1, nb = cur ^ 1;
#pragma unroll
            for (int part = 0; part < 2; ++part) {
                int c = part * 256 + tid;
                int row = c >> 3, sw = (c & 7) ^ (row & 7);
                gload_lds16(kb  + hb + (size_t)(jb * 64 + row) * DD + sw * 8, &Kt[nb][(part * 256 + cb) * 8]);
                gload_lds16(vtb + hb + (size_t)row * TT + jb * 64 + sw * 8,   &Vs[nb][(part * 256 + cb) * 8]);
            }
        }
        if (j < nt_w) {
            // ---- S^T = K Q^T : per lane one q-column (q = qw+l31), 32 key-rows ----
            f32x16 s0, s1;
#pragma unroll
            for (int r = 0; r < 16; ++r) { s0[r] = 0.f; s1[r] = 0.f; }
            __builtin_amdgcn_s_setprio(1);
#pragma unroll
            for (int df = 0; df < 4; ++df) {
                int colsw = df * 2 + h;
                int sw = (colsw ^ (l31 & 7)) * 8;
                short8 k0 = *(const short8*)&Kt[cur][l31 * 64 + sw];
                short8 k1 = *(const short8*)&Kt[cur][(l31 + 32) * 64 + sw];
                s0 = __builtin_amdgcn_mfma_f32_32x32x16_bf16(k0, qf[df], s0, 0, 0, 0);
                s1 = __builtin_amdgcn_mfma_f32_32x32x16_bf16(k1, qf[df], s1, 0, 0, 0);
            }
            __builtin_amdgcn_s_setprio(0);

            // ---- causal mask (only the warp's diagonal tile) ----
            if (j == nt_w - 1) {
                int qrel = qw + l31 - j * 64;
#pragma unroll
                for (int r = 0; r < 16; ++r) {
                    int kk = (r & 3) + 8 * (r >> 2) + 4 * h;
                    if (kk      > qrel) s0[r] = -1e30f;
                    if (kk + 32 > qrel) s1[r] = -1e30f;
                }
            }

            // ---- online softmax, defer-max (THR=8) ----
            float pm = -1e30f;
#pragma unroll
            for (int r = 0; r < 16; ++r) pm = fmaxf(pm, fmaxf(s0[r], s1[r]));
            pm = fmaxf(pm, __shfl_xor(pm, 32));
            if (!__all(pm <= mrun + 8.f)) {
                float mnew = fmaxf(mrun, pm);
                float sc = __expf(mrun - mnew);
                mrun = mnew;
                lrun *= sc;
#pragma unroll
                for (int r = 0; r < 16; ++r) {   // rare: broadcast softmax-layout -> C-layout
                    float scr = __shfl(sc, (r & 3) + 8 * (r >> 2) + 4 * h);
                    o0[r] *= scr; o1[r] *= scr;
                }
            }
            float sum = 0.f;
#pragma unroll
            for (int r = 0; r < 16; ++r) {
                float p0 = __expf(s0[r] - mrun); s0[r] = p0; sum += p0;
                float p1 = __expf(s1[r] - mrun); s1[r] = p1; sum += p1;
            }
            sum += __shfl_xor(sum, 32);
            lrun += sum;

            // ---- pack P -> bf16 A-frags (16 cvt_pk + 8 shfl) and PV ----
            __builtin_amdgcn_s_setprio(1);
#pragma unroll
            for (int f = 0; f < 4; ++f) {
                const f32x16& P = (f >= 2) ? s1 : s0;
                u32 A0, A1, B0, B1;
                if (f & 1) { A0 = cvtpk(P[8],  P[9]);  A1 = cvtpk(P[10], P[11]);
                             B0 = cvtpk(P[12], P[13]); B1 = cvtpk(P[14], P[15]); }
                else       { A0 = cvtpk(P[0],  P[1]);  A1 = cvtpk(P[2],  P[3]);
                             B0 = cvtpk(P[4],  P[5]);  B1 = cvtpk(P[6],  P[7]);  }
                u32 U0 = h ? B0 : A0, U1 = h ? B1 : A1;   // own half's words
                u32 V0 = h ? A0 : B0, V1 = h ? A1 : B1;   // export to partner half
                u32 W0 = (u32)__shfl_xor((int)V0, 32);
                u32 W1 = (u32)__shfl_xor((int)V1, 32);
                union { u32 u[4]; short8 s; } pa;
                pa.u[0] = h ? W0 : U0; pa.u[1] = h ? W1 : U1;
                pa.u[2] = h ? U0 : W0; pa.u[3] = h ? U1 : W1;
#pragma unroll
                for (int dt = 0; dt < 2; ++dt) {
                    int row = dt * 32 + l31;
                    short8 vf = *(const short8*)&Vs[cur][row * 64 + (((f * 2 + h) ^ (row & 7)) * 8)];
                    if (dt == 0) o0 = __builtin_amdgcn_mfma_f32_32x32x16_bf16(pa.s, vf, o0, 0, 0, 0);
                    else         o1 = __builtin_amdgcn_mfma_f32_32x32x16_bf16(pa.s, vf, o1, 0, 0, 0);
                }
            }
            __builtin_amdgcn_s_setprio(0);
        }
        cur ^= 1;
    }

    // ---- epilogue: O /= l, write [B*T][C] bf16 ----
    const int b = bh >> 4, head = bh & 15;
    float linv = 1.f / lrun;
#pragma unroll
    for (int r = 0; r < 16; ++r) {
        float li = __shfl(linv, (r & 3) + 8 * (r >> 2) + 4 * h);
        int q = qw + (r & 3) + 8 * (r >> 2) + 4 * h;
        size_t rb = ((size_t)(b * TT + q)) * CC + head * 64;
        ob[rb + l31]      = f2bf(o0[r] * li);
        ob[rb + 32 + l31] = f2bf(o1[r] * li);
    }
}

// ---------- launch ----------
extern "C" void kernel_launch(void* const* d_in, const int* in_sizes, int n_in,
                              void* d_out, int out_size, void* d_ws, size_t ws_size,
                              hipStream_t stream) {
    const float* x     = (const float*)d_in[0];
    const float* Wqkv  = (const float*)d_in[1];
    const float* bqkv  = (const float*)d_in[2];
    const float* Wproj = (const float*)d_in[3];
    const float* bproj = (const float*)d_in[4];
    float* out = (float*)d_out;

    char* ws = (char*)d_ws;
    u16* xb    = (u16*)(ws + 0);          // 16 MB (reused as ob after GEMM1)
    u16* wqkvT = (u16*)(ws + 16777216);   //  6 MB
    u16* wprojT= (u16*)(ws + 23068672);   //  2 MB
    u16* qb    = (u16*)(ws + 25165824);   // 16 MB
    u16* kb    = (u16*)(ws + 41943040);   // 16 MB
    u16* vtb   = (u16*)(ws + 58720256);   // 16 MB  [bh][d][t]
    u16* ob    = xb;                      // alias: x dead after GEMM1

    k_cvt_x<<<dim3(MM * CC / (256 * 8)), 256, 0, stream>>>(x, xb);
    k_transpose_cvt<<<dim3(N1 * CC / (256 * 8)), 256, 0, stream>>>(Wqkv, wqkvT, CC, N1);
    k_transpose_cvt<<<dim3(CC * CC / (256 * 8)), 256, 0, stream>>>(Wproj, wprojT, CC, CC);
    k_gemm_qkv<<<dim3(MM / 128, N1 / 128), 256, 0, stream>>>(xb, wqkvT, bqkv, qb, kb, vtb);
    k_attn2<<<dim3(BB * HH, TT / 128), 256, 0, stream>>>(qb, kb, vtb, ob);
    k_gemm_proj<<<dim3(MM / 128, CC / 128), 256, 0, stream>>>(ob, wprojT, bproj, out);
}

// Round 3
// 290.382 us; speedup vs baseline: 1.8654x; 1.0660x over previous
//
#include <hip/hip_runtime.h>

#define DEV __device__ __forceinline__

using u16 = unsigned short;
using u32 = unsigned int;
typedef __attribute__((ext_vector_type(8)))  short  short8;   // 8 bf16 (4 VGPRs) MFMA frag
typedef __attribute__((ext_vector_type(8)))  u16    ushort8;
typedef __attribute__((ext_vector_type(4)))  u16    us4;
typedef __attribute__((ext_vector_type(4)))  float  f32x4;
typedef __attribute__((ext_vector_type(16))) float  f32x16;

// ---------- problem constants ----------
constexpr int BB = 4;          // batch
constexpr int TT = 2048;       // seq len
constexpr int CC = 1024;       // embed dim
constexpr int HH = 16;         // heads
constexpr int DD = 64;         // head dim
constexpr int MM = BB * TT;    // 8192 rows
constexpr int N1 = 3 * CC;     // 3072 (qkv)

// fp32 -> bf16 round-to-nearest-even
DEV u16 f2bf(float f) {
    unsigned u = __float_as_uint(f);
    unsigned r = (u + 0x7FFFu + ((u >> 16) & 1u)) >> 16;
    return (u16)r;
}

DEV u32 cvtpk(float lo, float hi) {
    u32 r;
    asm("v_cvt_pk_bf16_f32 %0, %1, %2" : "=v"(r) : "v"(lo), "v"(hi));
    return r;
}

DEV void gload_lds16(const void* g, void* l) {
    __builtin_amdgcn_global_load_lds((const __attribute__((address_space(1))) void*)g,
                                     (__attribute__((address_space(3))) void*)l,
                                     16, 0, 0);
}

// ---------- converters ----------
__global__ void k_cvt_x(const float* __restrict__ src, u16* __restrict__ dst) {
    int i = (blockIdx.x * 256 + threadIdx.x) * 8;
    f32x4 a = *(const f32x4*)(src + i);
    f32x4 b = *(const f32x4*)(src + i + 4);
    ushort8 u;
    u[0] = f2bf(a[0]); u[1] = f2bf(a[1]); u[2] = f2bf(a[2]); u[3] = f2bf(a[3]);
    u[4] = f2bf(b[0]); u[5] = f2bf(b[1]); u[6] = f2bf(b[2]); u[7] = f2bf(b[3]);
    *(ushort8*)(dst + i) = u;
}

// LDS-tiled coalesced transpose+convert: dst[n][k] = bf16(src[k][n])
// src: [Kd][Nd] f32, dst: [Nd][Kd] bf16. grid (Nd/64, Kd/64) x 256 threads.
__global__ __launch_bounds__(256) void k_transpose_cvt2(const float* __restrict__ src,
                                                        u16* __restrict__ dst,
                                                        int Kd, int Nd) {
    __shared__ u16 tile[64][66];
    const int t = threadIdx.x;
    const int k0 = blockIdx.y * 64, n0 = blockIdx.x * 64;
    const int c = t & 63, r0 = (t >> 6) * 16;
#pragma unroll
    for (int i = 0; i < 16; ++i)
        tile[r0 + i][c] = f2bf(src[(size_t)(k0 + r0 + i) * Nd + n0 + c]);
    __syncthreads();
    const int kc = (t & 7) * 8, nn = t >> 3;   // nn in 0..31
#pragma unroll
    for (int h = 0; h < 2; ++h) {
        int n = nn + h * 32;
        ushort8 v;
#pragma unroll
        for (int j = 0; j < 8; ++j) v[j] = tile[kc + j][n];
        *(ushort8*)(dst + (size_t)(n0 + n) * Kd + k0 + kc) = v;
    }
}

// ---------- 128x128 GEMM mainloop, 2-phase prefetch double-buffer ----------
// A: [*,1024] bf16 row-major (pre-offset). B: [*,1024] bf16 = B^T layout (pre-offset).
DEV void stage_tile(const u16* __restrict__ Ag, const u16* __restrict__ Bg, int kt,
                    u16* As, u16* Bs, int lane, int wid) {
#pragma unroll
    for (int p = 0; p < 2; ++p) {
        int cb = p * 256 + wid * 64;             // wave-uniform chunk base
        int chunk = cb + lane;
        int row = chunk >> 2, kc = chunk & 3;
        gload_lds16(Ag + (size_t)row * 1024 + kt + kc * 8, As + cb * 8);
        gload_lds16(Bg + (size_t)row * 1024 + kt + kc * 8, Bs + cb * 8);
    }
}

DEV void gemm_mainloop2(const u16* __restrict__ Ag, const u16* __restrict__ Bg,
                        u16 (*As)[4096], u16 (*Bs)[4096], f32x4 acc[4][4]) {
    const int tid = threadIdx.x, lane = tid & 63, wid = tid >> 6;
    const int wr = wid >> 1, wc = wid & 1;
    stage_tile(Ag, Bg, 0, As[0], Bs[0], lane, wid);
    int cur = 0;
#pragma unroll 1
    for (int kt = 0; kt < 1024; kt += 32) {
        asm volatile("s_waitcnt vmcnt(0)" ::: "memory");  // own stage loads landed
        __syncthreads();                                   // all waves: buf[cur] ready, buf[cur^1] reads done
        if (kt + 32 < 1024)
            stage_tile(Ag, Bg, kt + 32, As[cur ^ 1], Bs[cur ^ 1], lane, wid);  // flies under MFMA
        short8 aF[4], bF[4];
#pragma unroll
        for (int m = 0; m < 4; ++m)
            aF[m] = *(const short8*)&As[cur][(wr * 64 + m * 16 + (lane & 15)) * 32 + (lane >> 4) * 8];
#pragma unroll
        for (int n = 0; n < 4; ++n)
            bF[n] = *(const short8*)&Bs[cur][(wc * 64 + n * 16 + (lane & 15)) * 32 + (lane >> 4) * 8];
        __builtin_amdgcn_s_setprio(1);
#pragma unroll
        for (int m = 0; m < 4; ++m)
#pragma unroll
            for (int n = 0; n < 4; ++n)
                acc[m][n] = __builtin_amdgcn_mfma_f32_16x16x32_bf16(aF[m], bF[n], acc[m][n], 0, 0, 0);
        __builtin_amdgcn_s_setprio(0);
        cur ^= 1;
    }
}

// GEMM1: qkv = x @ W_qkv + b; scatter q (x0.125), k row-major, v TRANSPOSED [bh][d][t]
__global__ __launch_bounds__(256) void k_gemm_qkv(const u16* __restrict__ xb,
                                                  const u16* __restrict__ wt,
                                                  const float* __restrict__ bqkv,
                                                  u16* __restrict__ qb,
                                                  u16* __restrict__ kb,
                                                  u16* __restrict__ vtb) {
    __shared__ u16 As[2][4096], Bs[2][4096];
    f32x4 acc[4][4];
#pragma unroll
    for (int m = 0; m < 4; ++m)
#pragma unroll
        for (int n = 0; n < 4; ++n) acc[m][n] = (f32x4){0.f, 0.f, 0.f, 0.f};
    // XCD-aware swizzle: grid (64,24), nwg=1536, 1536/8=192
    const int orig = blockIdx.y * 64 + blockIdx.x;
    const int swz = (orig & 7) * 192 + (orig >> 3);
    const int rowBase = (swz & 63) * 128, colBase = (swz >> 6) * 128;
    gemm_mainloop2(xb + (size_t)rowBase * 1024, wt + (size_t)colBase * 1024, As, Bs, acc);
    const int lane = threadIdx.x & 63, wid = threadIdx.x >> 6;
    const int wr = wid >> 1, wc = wid & 1;
#pragma unroll
    for (int n = 0; n < 4; ++n) {
        int gn = colBase + wc * 64 + n * 16 + (lane & 15);
        float bias = bqkv[gn];
        int which = gn >> 10, cc = gn & 1023, hh = cc >> 6, d = cc & 63;   // wave-uniform which
        if (which == 2) {
            u16* vdst = vtb + ((size_t)hh * DD + d) * TT;   // + b*HH*DD*TT added below
#pragma unroll
            for (int m = 0; m < 4; ++m) {
                int gm = rowBase + wr * 64 + m * 16 + (lane >> 4) * 4;
                int b = gm >> 11, t = gm & 2047;
                us4 pv;
#pragma unroll
                for (int r = 0; r < 4; ++r) pv[r] = f2bf(acc[m][n][r] + bias);
                *(us4*)(vdst + (size_t)b * (HH * DD * TT) + t) = pv;
            }
        } else {
            u16* dst = (which == 0 ? qb : kb);
            float sc = (which == 0) ? 0.125f : 1.0f;
#pragma unroll
            for (int m = 0; m < 4; ++m) {
#pragma unroll
                for (int r = 0; r < 4; ++r) {
                    int gm = rowBase + wr * 64 + m * 16 + (lane >> 4) * 4 + r;
                    int b = gm >> 11, t = gm & 2047;
                    dst[(((size_t)b * HH + hh) * TT + t) * DD + d] = f2bf((acc[m][n][r] + bias) * sc);
                }
            }
        }
    }
}

// GEMM2: out = o @ W_proj + b; fp32 output
__global__ __launch_bounds__(256) void k_gemm_proj(const u16* __restrict__ ob,
                                                   const u16* __restrict__ wt,
                                                   const float* __restrict__ bproj,
                                                   float* __restrict__ out) {
    __shared__ u16 As[2][4096], Bs[2][4096];
    f32x4 acc[4][4];
#pragma unroll
    for (int m = 0; m < 4; ++m)
#pragma unroll
        for (int n = 0; n < 4; ++n) acc[m][n] = (f32x4){0.f, 0.f, 0.f, 0.f};
    // XCD-aware swizzle: grid (64,8), nwg=512, 512/8=64
    const int orig = blockIdx.y * 64 + blockIdx.x;
    const int swz = (orig & 7) * 64 + (orig >> 3);
    const int rowBase = (swz & 63) * 128, colBase = (swz >> 6) * 128;
    gemm_mainloop2(ob + (size_t)rowBase * 1024, wt + (size_t)colBase * 1024, As, Bs, acc);
    const int lane = threadIdx.x & 63, wid = threadIdx.x >> 6;
    const int wr = wid >> 1, wc = wid & 1;
#pragma unroll
    for (int n = 0; n < 4; ++n) {
        int gn = colBase + wc * 64 + n * 16 + (lane & 15);
        float bias = bproj[gn];
#pragma unroll
        for (int m = 0; m < 4; ++m) {
#pragma unroll
            for (int r = 0; r < 4; ++r) {
                int gm = rowBase + wr * 64 + m * 16 + (lane >> 4) * 4 + r;
                out[(size_t)gm * 1024 + gn] = acc[m][n][r] + bias;
            }
        }
    }
}

// ---------- causal flash attention, 4 warps x 32 q-rows, KVBLK=64, swapped QK^T ----------
// q,k: [bh][t][64] bf16 (q pre-scaled by 0.125). vt: [bh][64][t] bf16. o: [B*T][C] bf16.
__global__ __launch_bounds__(256) void k_attn2(const u16* __restrict__ qb,
                                               const u16* __restrict__ kb,
                                               const u16* __restrict__ vtb,
                                               u16* __restrict__ ob) {
    __shared__ u16 Kt[2][4096];   // [key 64][d 64], 16B-chunk XOR-swizzled
    __shared__ u16 Vs[2][4096];   // [d 64][key 64], 16B-chunk XOR-swizzled

    const int tid = threadIdx.x, lane = tid & 63, w = tid >> 6;
    const int h = lane >> 5, l31 = lane & 31;
    const int bh = blockIdx.x;
    const int qi = 15 - blockIdx.y;           // heavy blocks dispatched first
    const size_t hb = (size_t)bh * (TT * DD);
    const int qw = qi * 128 + w * 32;         // warp's first q row
    const int nt_blk = 2 * qi + 2;            // KV tiles for the block
    const int nt_w = (qw >> 6) + 1;           // KV tiles this warp computes
    const int cb = tid & ~63;                 // wave-uniform chunk base

    // Q B-frags: col q = qw + l31, k(d) = df*16 + h*8 + j
    short8 qf[4];
#pragma unroll
    for (int df = 0; df < 4; ++df)
        qf[df] = *(const short8*)(qb + hb + (size_t)(qw + l31) * DD + df * 16 + h * 8);

    f32x16 o0, o1;
#pragma unroll
    for (int r = 0; r < 16; ++r) { o0[r] = 0.f; o1[r] = 0.f; }
    float mrun = -1e30f, lrun = 0.f;

    // stage tile 0 into buf 0 (pre-swizzled global source, linear LDS dest)
#pragma unroll
    for (int part = 0; part < 2; ++part) {
        int c = part * 256 + tid;
        int row = c >> 3, sw = (c & 7) ^ (row & 7);
        gload_lds16(kb  + hb + (size_t)row * DD + sw * 8,      &Kt[0][(part * 256 + cb) * 8]);
        gload_lds16(vtb + hb + (size_t)row * TT + sw * 8,      &Vs[0][(part * 256 + cb) * 8]);
    }

    int cur = 0;
    for (int j = 0; j < nt_blk; ++j) {
        asm volatile("s_waitcnt vmcnt(0)" ::: "memory");   // buf[cur] staged
        __syncthreads();                                    // all waves staged; WAR safe
        if (j + 1 < nt_blk) {                               // prefetch next tile (flies under compute)
            const int jb = j + 1, nb = cur ^ 1;
#pragma unroll
            for (int part = 0; part < 2; ++part) {
                int c = part * 256 + tid;
                int row = c >> 3, sw = (c & 7) ^ (row & 7);
                gload_lds16(kb  + hb + (size_t)(jb * 64 + row) * DD + sw * 8, &Kt[nb][(part * 256 + cb) * 8]);
                gload_lds16(vtb + hb + (size_t)row * TT + jb * 64 + sw * 8,   &Vs[nb][(part * 256 + cb) * 8]);
            }
        }
        if (j < nt_w) {
            // ---- S^T = K Q^T : per lane one q-column (q = qw+l31), 32 key-rows ----
            f32x16 s0, s1;
#pragma unroll
            for (int r = 0; r < 16; ++r) { s0[r] = 0.f; s1[r] = 0.f; }
            __builtin_amdgcn_s_setprio(1);
#pragma unroll
            for (int df = 0; df < 4; ++df) {
                int colsw = df * 2 + h;
                int sw = (colsw ^ (l31 & 7)) * 8;
                short8 k0 = *(const short8*)&Kt[cur][l31 * 64 + sw];
                short8 k1 = *(const short8*)&Kt[cur][(l31 + 32) * 64 + sw];
                s0 = __builtin_amdgcn_mfma_f32_32x32x16_bf16(k0, qf[df], s0, 0, 0, 0);
                s1 = __builtin_amdgcn_mfma_f32_32x32x16_bf16(k1, qf[df], s1, 0, 0, 0);
            }
            __builtin_amdgcn_s_setprio(0);

            // ---- causal mask (only the warp's diagonal tile) ----
            if (j == nt_w - 1) {
                int qrel = qw + l31 - j * 64;
#pragma unroll
                for (int r = 0; r < 16; ++r) {
                    int kk = (r & 3) + 8 * (r >> 2) + 4 * h;
                    if (kk      > qrel) s0[r] = -1e30f;
                    if (kk + 32 > qrel) s1[r] = -1e30f;
                }
            }

            // ---- online softmax, defer-max (THR=8) ----
            float pm = -1e30f;
#pragma unroll
            for (int r = 0; r < 16; ++r) pm = fmaxf(pm, fmaxf(s0[r], s1[r]));
            pm = fmaxf(pm, __shfl_xor(pm, 32));
            if (!__all(pm <= mrun + 8.f)) {
                float mnew = fmaxf(mrun, pm);
                float sc = __expf(mrun - mnew);
                mrun = mnew;
                lrun *= sc;
#pragma unroll
                for (int r = 0; r < 16; ++r) {   // rare: broadcast softmax-layout -> C-layout
                    float scr = __shfl(sc, (r & 3) + 8 * (r >> 2) + 4 * h);
                    o0[r] *= scr; o1[r] *= scr;
                }
            }
            float sum = 0.f;
#pragma unroll
            for (int r = 0; r < 16; ++r) {
                float p0 = __expf(s0[r] - mrun); s0[r] = p0; sum += p0;
                float p1 = __expf(s1[r] - mrun); s1[r] = p1; sum += p1;
            }
            sum += __shfl_xor(sum, 32);
            lrun += sum;

            // ---- pack P -> bf16 A-frags (16 cvt_pk + 8 shfl) and PV ----
            __builtin_amdgcn_s_setprio(1);
#pragma unroll
            for (int f = 0; f < 4; ++f) {
                const f32x16& P = (f >= 2) ? s1 : s0;
                u32 A0, A1, B0, B1;
                if (f & 1) { A0 = cvtpk(P[8],  P[9]);  A1 = cvtpk(P[10], P[11]);
                             B0 = cvtpk(P[12], P[13]); B1 = cvtpk(P[14], P[15]); }
                else       { A0 = cvtpk(P[0],  P[1]);  A1 = cvtpk(P[2],  P[3]);
                             B0 = cvtpk(P[4],  P[5]);  B1 = cvtpk(P[6],  P[7]);  }
                u32 U0 = h ? B0 : A0, U1 = h ? B1 : A1;   // own half's words
                u32 V0 = h ? A0 : B0, V1 = h ? A1 : B1;   // export to partner half
                u32 W0 = (u32)__shfl_xor((int)V0, 32);
                u32 W1 = (u32)__shfl_xor((int)V1, 32);
                union { u32 u[4]; short8 s; } pa;
                pa.u[0] = h ? W0 : U0; pa.u[1] = h ? W1 : U1;
                pa.u[2] = h ? U0 : W0; pa.u[3] = h ? U1 : W1;
#pragma unroll
                for (int dt = 0; dt < 2; ++dt) {
                    int row = dt * 32 + l31;
                    short8 vf = *(const short8*)&Vs[cur][row * 64 + (((f * 2 + h) ^ (row & 7)) * 8)];
                    if (dt == 0) o0 = __builtin_amdgcn_mfma_f32_32x32x16_bf16(pa.s, vf, o0, 0, 0, 0);
                    else         o1 = __builtin_amdgcn_mfma_f32_32x32x16_bf16(pa.s, vf, o1, 0, 0, 0);
                }
            }
            __builtin_amdgcn_s_setprio(0);
        }
        cur ^= 1;
    }

    // ---- epilogue: O /= l, write [B*T][C] bf16 ----
    const int b = bh >> 4, head = bh & 15;
    float linv = 1.f / lrun;
#pragma unroll
    for (int r = 0; r < 16; ++r) {
        float li = __shfl(linv, (r & 3) + 8 * (r >> 2) + 4 * h);
        int q = qw + (r & 3) + 8 * (r >> 2) + 4 * h;
        size_t rb = ((size_t)(b * TT + q)) * CC + head * 64;
        ob[rb + l31]      = f2bf(o0[r] * li);
        ob[rb + 32 + l31] = f2bf(o1[r] * li);
    }
}

// ---------- launch ----------
extern "C" void kernel_launch(void* const* d_in, const int* in_sizes, int n_in,
                              void* d_out, int out_size, void* d_ws, size_t ws_size,
                              hipStream_t stream) {
    const float* x     = (const float*)d_in[0];
    const float* Wqkv  = (const float*)d_in[1];
    const float* bqkv  = (const float*)d_in[2];
    const float* Wproj = (const float*)d_in[3];
    const float* bproj = (const float*)d_in[4];
    float* out = (float*)d_out;

    char* ws = (char*)d_ws;
    u16* xb    = (u16*)(ws + 0);          // 16 MB (reused as ob after GEMM1)
    u16* wqkvT = (u16*)(ws + 16777216);   //  6 MB
    u16* wprojT= (u16*)(ws + 23068672);   //  2 MB
    u16* qb    = (u16*)(ws + 25165824);   // 16 MB
    u16* kb    = (u16*)(ws + 41943040);   // 16 MB
    u16* vtb   = (u16*)(ws + 58720256);   // 16 MB  [bh][d][t]
    u16* ob    = xb;                      // alias: x dead after GEMM1

    k_cvt_x<<<dim3(MM * CC / (256 * 8)), 256, 0, stream>>>(x, xb);
    k_transpose_cvt2<<<dim3(N1 / 64, CC / 64), 256, 0, stream>>>(Wqkv, wqkvT, CC, N1);
    k_transpose_cvt2<<<dim3(CC / 64, CC / 64), 256, 0, stream>>>(Wproj, wprojT, CC, CC);
    k_gemm_qkv<<<dim3(MM / 128, N1 / 128), 256, 0, stream>>>(xb, wqkvT, bqkv, qb, kb, vtb);
    k_attn2<<<dim3(BB * HH, TT / 128), 256, 0, stream>>>(qb, kb, vtb, ob);
    k_gemm_proj<<<dim3(MM / 128, CC / 128), 256, 0, stream>>>(ob, wprojT, bproj, out);
}

// Round 4
// 270.355 us; speedup vs baseline: 2.0036x; 1.0741x over previous
//
#include <hip/hip_runtime.h>

#define DEV __device__ __forceinline__

using u16 = unsigned short;
using u32 = unsigned int;
typedef __attribute__((ext_vector_type(8)))  short  short8;   // 8 bf16 (4 VGPRs) MFMA frag
typedef __attribute__((ext_vector_type(8)))  u16    ushort8;
typedef __attribute__((ext_vector_type(4)))  u16    us4;
typedef __attribute__((ext_vector_type(4)))  float  f32x4;
typedef __attribute__((ext_vector_type(16))) float  f32x16;

// ---------- problem constants ----------
constexpr int BB = 4;          // batch
constexpr int TT = 2048;       // seq len
constexpr int CC = 1024;       // embed dim
constexpr int HH = 16;         // heads
constexpr int DD = 64;         // head dim
constexpr int MM = BB * TT;    // 8192 rows
constexpr int N1 = 3 * CC;     // 3072 (qkv)

// fp32 -> bf16 round-to-nearest-even
DEV u16 f2bf(float f) {
    unsigned u = __float_as_uint(f);
    unsigned r = (u + 0x7FFFu + ((u >> 16) & 1u)) >> 16;
    return (u16)r;
}

DEV u32 cvtpk(float lo, float hi) {
    u32 r;
    asm("v_cvt_pk_bf16_f32 %0, %1, %2" : "=v"(r) : "v"(lo), "v"(hi));
    return r;
}

DEV void gload_lds16(const void* g, void* l) {
    __builtin_amdgcn_global_load_lds((const __attribute__((address_space(1))) void*)g,
                                     (__attribute__((address_space(3))) void*)l,
                                     16, 0, 0);
}

// ---------- converters ----------
__global__ void k_cvt_x(const float* __restrict__ src, u16* __restrict__ dst) {
    int i = (blockIdx.x * 256 + threadIdx.x) * 8;
    f32x4 a = *(const f32x4*)(src + i);
    f32x4 b = *(const f32x4*)(src + i + 4);
    ushort8 u;
    u[0] = f2bf(a[0]); u[1] = f2bf(a[1]); u[2] = f2bf(a[2]); u[3] = f2bf(a[3]);
    u[4] = f2bf(b[0]); u[5] = f2bf(b[1]); u[6] = f2bf(b[2]); u[7] = f2bf(b[3]);
    *(ushort8*)(dst + i) = u;
}

// LDS-tiled coalesced transpose+convert: dst[n][k] = bf16(src[k][n])
__global__ __launch_bounds__(256) void k_transpose_cvt2(const float* __restrict__ src,
                                                        u16* __restrict__ dst,
                                                        int Kd, int Nd) {
    __shared__ u16 tile[64][66];
    const int t = threadIdx.x;
    const int k0 = blockIdx.y * 64, n0 = blockIdx.x * 64;
    const int c = t & 63, r0 = (t >> 6) * 16;
#pragma unroll
    for (int i = 0; i < 16; ++i)
        tile[r0 + i][c] = f2bf(src[(size_t)(k0 + r0 + i) * Nd + n0 + c]);
    __syncthreads();
    const int kc = (t & 7) * 8, nn = t >> 3;   // nn in 0..31
#pragma unroll
    for (int h = 0; h < 2; ++h) {
        int n = nn + h * 32;
        ushort8 v;
#pragma unroll
        for (int j = 0; j < 8; ++j) v[j] = tile[kc + j][n];
        *(ushort8*)(dst + (size_t)(n0 + n) * Kd + k0 + kc) = v;
    }
}

// ---------- 128x128 GEMM mainloop, depth-2 prefetch (3 LDS buffers, counted vmcnt) ----------
DEV void stage_tile(const u16* __restrict__ Ag, const u16* __restrict__ Bg, int kt,
                    u16* As, u16* Bs, int lane, int wid) {
#pragma unroll
    for (int p = 0; p < 2; ++p) {
        int cb = p * 256 + wid * 64;             // wave-uniform chunk base
        int chunk = cb + lane;
        int row = chunk >> 2, kc = chunk & 3;
        gload_lds16(Ag + (size_t)row * 1024 + kt + kc * 8, As + cb * 8);
        gload_lds16(Bg + (size_t)row * 1024 + kt + kc * 8, Bs + cb * 8);
    }
}

DEV void gemm_mainloop3(const u16* __restrict__ Ag, const u16* __restrict__ Bg,
                        u16 (*As)[4096], u16 (*Bs)[4096], f32x4 acc[4][4]) {
    const int tid = threadIdx.x, lane = tid & 63, wid = tid >> 6;
    const int wr = wid >> 1, wc = wid & 1;
    stage_tile(Ag, Bg, 0,  As[0], Bs[0], lane, wid);
    stage_tile(Ag, Bg, 32, As[1], Bs[1], lane, wid);
    int cur = 0;
#pragma unroll 1
    for (int t = 0; t < 32; ++t) {
        // own stage of tile t (oldest 4 loads) landed; tile t+1's 4 may stay in flight
        if (t == 31) asm volatile("s_waitcnt vmcnt(0)" ::: "memory");
        else         asm volatile("s_waitcnt vmcnt(4)" ::: "memory");
        __builtin_amdgcn_s_barrier();   // raw barrier: no implicit vmcnt drain
        if (t + 2 < 32) {
            int nb = cur + 2; if (nb > 2) nb -= 3;
            stage_tile(Ag, Bg, (t + 2) * 32, As[nb], Bs[nb], lane, wid);
        }
        short8 aF[4], bF[4];
#pragma unroll
        for (int m = 0; m < 4; ++m)
            aF[m] = *(const short8*)&As[cur][(wr * 64 + m * 16 + (lane & 15)) * 32 + (lane >> 4) * 8];
#pragma unroll
        for (int n = 0; n < 4; ++n)
            bF[n] = *(const short8*)&Bs[cur][(wc * 64 + n * 16 + (lane & 15)) * 32 + (lane >> 4) * 8];
        __builtin_amdgcn_s_setprio(1);
#pragma unroll
        for (int m = 0; m < 4; ++m)
#pragma unroll
            for (int n = 0; n < 4; ++n)
                acc[m][n] = __builtin_amdgcn_mfma_f32_16x16x32_bf16(aF[m], bF[n], acc[m][n], 0, 0, 0);
        __builtin_amdgcn_s_setprio(0);
        cur = (cur == 2) ? 0 : cur + 1;
    }
}

// GEMM1: qkv = x @ W_qkv + b; scatter q (x0.125), k row-major, v TRANSPOSED [bh][d][t]
__global__ __launch_bounds__(256) void k_gemm_qkv(const u16* __restrict__ xb,
                                                  const u16* __restrict__ wt,
                                                  const float* __restrict__ bqkv,
                                                  u16* __restrict__ qb,
                                                  u16* __restrict__ kb,
                                                  u16* __restrict__ vtb) {
    __shared__ u16 As[3][4096], Bs[3][4096];
    f32x4 acc[4][4];
#pragma unroll
    for (int m = 0; m < 4; ++m)
#pragma unroll
        for (int n = 0; n < 4; ++n) acc[m][n] = (f32x4){0.f, 0.f, 0.f, 0.f};
    // natural order: all XCDs sweep M together per N-panel; L3 absorbs x re-reads
    const int rowBase = blockIdx.x * 128, colBase = blockIdx.y * 128;
    gemm_mainloop3(xb + (size_t)rowBase * 1024, wt + (size_t)colBase * 1024, As, Bs, acc);
    const int lane = threadIdx.x & 63, wid = threadIdx.x >> 6;
    const int wr = wid >> 1, wc = wid & 1;
#pragma unroll
    for (int n = 0; n < 4; ++n) {
        int gn = colBase + wc * 64 + n * 16 + (lane & 15);
        float bias = bqkv[gn];
        int which = gn >> 10, cc = gn & 1023, hh = cc >> 6, d = cc & 63;   // wave-uniform which
        if (which == 2) {
            u16* vdst = vtb + ((size_t)hh * DD + d) * TT;
#pragma unroll
            for (int m = 0; m < 4; ++m) {
                int gm = rowBase + wr * 64 + m * 16 + (lane >> 4) * 4;
                int b = gm >> 11, t = gm & 2047;
                us4 pv;
#pragma unroll
                for (int r = 0; r < 4; ++r) pv[r] = f2bf(acc[m][n][r] + bias);
                *(us4*)(vdst + (size_t)b * (HH * DD * TT) + t) = pv;
            }
        } else {
            u16* dst = (which == 0 ? qb : kb);
            float sc = (which == 0) ? 0.125f : 1.0f;
#pragma unroll
            for (int m = 0; m < 4; ++m) {
#pragma unroll
                for (int r = 0; r < 4; ++r) {
                    int gm = rowBase + wr * 64 + m * 16 + (lane >> 4) * 4 + r;
                    int b = gm >> 11, t = gm & 2047;
                    dst[(((size_t)b * HH + hh) * TT + t) * DD + d] = f2bf((acc[m][n][r] + bias) * sc);
                }
            }
        }
    }
}

// GEMM2: out = o @ W_proj + b; fp32 output
__global__ __launch_bounds__(256) void k_gemm_proj(const u16* __restrict__ ob,
                                                   const u16* __restrict__ wt,
                                                   const float* __restrict__ bproj,
                                                   float* __restrict__ out) {
    __shared__ u16 As[3][4096], Bs[3][4096];
    f32x4 acc[4][4];
#pragma unroll
    for (int m = 0; m < 4; ++m)
#pragma unroll
        for (int n = 0; n < 4; ++n) acc[m][n] = (f32x4){0.f, 0.f, 0.f, 0.f};
    const int rowBase = blockIdx.x * 128, colBase = blockIdx.y * 128;
    gemm_mainloop3(ob + (size_t)rowBase * 1024, wt + (size_t)colBase * 1024, As, Bs, acc);
    const int lane = threadIdx.x & 63, wid = threadIdx.x >> 6;
    const int wr = wid >> 1, wc = wid & 1;
#pragma unroll
    for (int n = 0; n < 4; ++n) {
        int gn = colBase + wc * 64 + n * 16 + (lane & 15);
        float bias = bproj[gn];
#pragma unroll
        for (int m = 0; m < 4; ++m) {
#pragma unroll
            for (int r = 0; r < 4; ++r) {
                int gm = rowBase + wr * 64 + m * 16 + (lane >> 4) * 4 + r;
                out[(size_t)gm * 1024 + gn] = acc[m][n][r] + bias;
            }
        }
    }
}

// ---------- causal flash attention: 8 warps x 32 q-rows (QBLK=256), KVBLK=64 ----------
// q,k: [bh][t][64] bf16 (q pre-scaled by 0.125). vt: [bh][64][t] bf16. o: [B*T][C] bf16.
DEV void attn_stage(const u16* __restrict__ kb_hb, const u16* __restrict__ vtb_hb,
                    int j, u16* Kd, u16* Vd, int tid) {
    int row = tid >> 3, sw = (tid & 7) ^ (row & 7);
    int cb8 = (tid & ~63) * 8;                        // wave-uniform LDS chunk base (u16 idx)
    gload_lds16(kb_hb + (size_t)(j * 64 + row) * DD + sw * 8, Kd + cb8);
    gload_lds16(vtb_hb + (size_t)row * TT + j * 64 + sw * 8,  Vd + cb8);
}

__global__ __launch_bounds__(512) void k_attn2(const u16* __restrict__ qb,
                                               const u16* __restrict__ kb,
                                               const u16* __restrict__ vtb,
                                               u16* __restrict__ ob) {
    __shared__ u16 Kt[3][4096];   // [key 64][d 64], 16B-chunk XOR-swizzled
    __shared__ u16 Vs[3][4096];   // [d 64][key 64], 16B-chunk XOR-swizzled

    const int tid = threadIdx.x, lane = tid & 63, w = tid >> 6;
    const int h = lane >> 5, l31 = lane & 31;
    const int bh = blockIdx.x;
    const int qi = 7 - blockIdx.y;            // heavy blocks dispatched first
    const size_t hb = (size_t)bh * (TT * DD);
    const int qw = qi * 256 + w * 32;         // warp's first q row
    const int nt_blk = 4 * qi + 4;            // KV tiles for the block (>=4)
    const int nt_w = (qw >> 6) + 1;           // KV tiles this warp computes
    const u16* kb_hb = kb + hb;
    const u16* vtb_hb = vtb + hb;

    // Q B-frags: col q = qw + l31, k(d) = df*16 + h*8 + j
    short8 qf[4];
#pragma unroll
    for (int df = 0; df < 4; ++df)
        qf[df] = *(const short8*)(qb + hb + (size_t)(qw + l31) * DD + df * 16 + h * 8);

    f32x16 o0, o1;
#pragma unroll
    for (int r = 0; r < 16; ++r) { o0[r] = 0.f; o1[r] = 0.f; }
    float mrun = -1e30f, lrun = 0.f;

    attn_stage(kb_hb, vtb_hb, 0, Kt[0], Vs[0], tid);
    attn_stage(kb_hb, vtb_hb, 1, Kt[1], Vs[1], tid);

    int cur = 0;
    for (int j = 0; j < nt_blk; ++j) {
        // own tile-j loads (oldest 2) landed; tile j+1's 2 may stay in flight
        if (j == nt_blk - 1) asm volatile("s_waitcnt vmcnt(0)" ::: "memory");
        else                 asm volatile("s_waitcnt vmcnt(2)" ::: "memory");
        __builtin_amdgcn_s_barrier();
        if (j + 2 < nt_blk) {
            int nb = cur + 2; if (nb > 2) nb -= 3;
            attn_stage(kb_hb, vtb_hb, j + 2, Kt[nb], Vs[nb], tid);
        }
        if (j < nt_w) {
            // ---- S^T = K Q^T : per lane one q-column (q = qw+l31), 64 key-rows ----
            f32x16 s0, s1;
#pragma unroll
            for (int r = 0; r < 16; ++r) { s0[r] = 0.f; s1[r] = 0.f; }
            __builtin_amdgcn_s_setprio(1);
#pragma unroll
            for (int df = 0; df < 4; ++df) {
                int colsw = df * 2 + h;
                int sw = (colsw ^ (l31 & 7)) * 8;
                short8 k0 = *(const short8*)&Kt[cur][l31 * 64 + sw];
                short8 k1 = *(const short8*)&Kt[cur][(l31 + 32) * 64 + sw];
                s0 = __builtin_amdgcn_mfma_f32_32x32x16_bf16(k0, qf[df], s0, 0, 0, 0);
                s1 = __builtin_amdgcn_mfma_f32_32x32x16_bf16(k1, qf[df], s1, 0, 0, 0);
            }
            __builtin_amdgcn_s_setprio(0);

            // ---- causal mask (only the warp's diagonal tile) ----
            if (j == nt_w - 1) {
                int qrel = qw + l31 - j * 64;
#pragma unroll
                for (int r = 0; r < 16; ++r) {
                    int kk = (r & 3) + 8 * (r >> 2) + 4 * h;
                    if (kk      > qrel) s0[r] = -1e30f;
                    if (kk + 32 > qrel) s1[r] = -1e30f;
                }
            }

            // ---- online softmax, defer-max (THR=8) ----
            float pm = -1e30f;
#pragma unroll
            for (int r = 0; r < 16; ++r) pm = fmaxf(pm, fmaxf(s0[r], s1[r]));
            pm = fmaxf(pm, __shfl_xor(pm, 32));
            if (!__all(pm <= mrun + 8.f)) {
                float mnew = fmaxf(mrun, pm);
                float sc = __expf(mrun - mnew);
                mrun = mnew;
                lrun *= sc;
#pragma unroll
                for (int r = 0; r < 16; ++r) {   // rare: broadcast softmax-layout -> C-layout
                    float scr = __shfl(sc, (r & 3) + 8 * (r >> 2) + 4 * h);
                    o0[r] *= scr; o1[r] *= scr;
                }
            }
            float sum = 0.f;
#pragma unroll
            for (int r = 0; r < 16; ++r) {
                float p0 = __expf(s0[r] - mrun); s0[r] = p0; sum += p0;
                float p1 = __expf(s1[r] - mrun); s1[r] = p1; sum += p1;
            }
            sum += __shfl_xor(sum, 32);
            lrun += sum;

            // ---- pack P -> bf16 A-frags (16 cvt_pk + 8 shfl) and PV ----
            __builtin_amdgcn_s_setprio(1);
#pragma unroll
            for (int f = 0; f < 4; ++f) {
                const f32x16& P = (f >= 2) ? s1 : s0;
                u32 A0, A1, B0, B1;
                if (f & 1) { A0 = cvtpk(P[8],  P[9]);  A1 = cvtpk(P[10], P[11]);
                             B0 = cvtpk(P[12], P[13]); B1 = cvtpk(P[14], P[15]); }
                else       { A0 = cvtpk(P[0],  P[1]);  A1 = cvtpk(P[2],  P[3]);
                             B0 = cvtpk(P[4],  P[5]);  B1 = cvtpk(P[6],  P[7]);  }
                u32 U0 = h ? B0 : A0, U1 = h ? B1 : A1;   // own half's words
                u32 V0 = h ? A0 : B0, V1 = h ? A1 : B1;   // export to partner half
                u32 W0 = (u32)__shfl_xor((int)V0, 32);
                u32 W1 = (u32)__shfl_xor((int)V1, 32);
                union { u32 u[4]; short8 s; } pa;
                pa.u[0] = h ? W0 : U0; pa.u[1] = h ? W1 : U1;
                pa.u[2] = h ? U0 : W0; pa.u[3] = h ? U1 : W1;
#pragma unroll
                for (int dt = 0; dt < 2; ++dt) {
                    int row = dt * 32 + l31;
                    short8 vf = *(const short8*)&Vs[cur][row * 64 + (((f * 2 + h) ^ (row & 7)) * 8)];
                    if (dt == 0) o0 = __builtin_amdgcn_mfma_f32_32x32x16_bf16(pa.s, vf, o0, 0, 0, 0);
                    else         o1 = __builtin_amdgcn_mfma_f32_32x32x16_bf16(pa.s, vf, o1, 0, 0, 0);
                }
            }
            __builtin_amdgcn_s_setprio(0);
        }
        cur = (cur == 2) ? 0 : cur + 1;
    }

    // ---- epilogue: O /= l, write [B*T][C] bf16 ----
    const int b = bh >> 4, head = bh & 15;
    float linv = 1.f / lrun;
#pragma unroll
    for (int r = 0; r < 16; ++r) {
        float li = __shfl(linv, (r & 3) + 8 * (r >> 2) + 4 * h);
        int q = qw + (r & 3) + 8 * (r >> 2) + 4 * h;
        size_t rb = ((size_t)(b * TT + q)) * CC + head * 64;
        ob[rb + l31]      = f2bf(o0[r] * li);
        ob[rb + 32 + l31] = f2bf(o1[r] * li);
    }
}

// ---------- launch ----------
extern "C" void kernel_launch(void* const* d_in, const int* in_sizes, int n_in,
                              void* d_out, int out_size, void* d_ws, size_t ws_size,
                              hipStream_t stream) {
    const float* x     = (const float*)d_in[0];
    const float* Wqkv  = (const float*)d_in[1];
    const float* bqkv  = (const float*)d_in[2];
    const float* Wproj = (const float*)d_in[3];
    const float* bproj = (const float*)d_in[4];
    float* out = (float*)d_out;

    char* ws = (char*)d_ws;
    u16* xb    = (u16*)(ws + 0);          // 16 MB (reused as ob after GEMM1)
    u16* wqkvT = (u16*)(ws + 16777216);   //  6 MB
    u16* wprojT= (u16*)(ws + 23068672);   //  2 MB
    u16* qb    = (u16*)(ws + 25165824);   // 16 MB
    u16* kb    = (u16*)(ws + 41943040);   // 16 MB
    u16* vtb   = (u16*)(ws + 58720256);   // 16 MB  [bh][d][t]
    u16* ob    = xb;                      // alias: x dead after GEMM1

    k_cvt_x<<<dim3(MM * CC / (256 * 8)), 256, 0, stream>>>(x, xb);
    k_transpose_cvt2<<<dim3(N1 / 64, CC / 64), 256, 0, stream>>>(Wqkv, wqkvT, CC, N1);
    k_transpose_cvt2<<<dim3(CC / 64, CC / 64), 256, 0, stream>>>(Wproj, wprojT, CC, CC);
    k_gemm_qkv<<<dim3(MM / 128, N1 / 128), 256, 0, stream>>>(xb, wqkvT, bqkv, qb, kb, vtb);
    k_attn2<<<dim3(BB * HH, TT / 256), 512, 0, stream>>>(qb, kb, vtb, ob);
    k_gemm_proj<<<dim3(MM / 128, CC / 128), 256, 0, stream>>>(ob, wprojT, bproj, out);
}

// Round 6
// 251.618 us; speedup vs baseline: 2.1528x; 1.0745x over previous
//
#include <hip/hip_runtime.h>

#define DEV __device__ __forceinline__

using u16 = unsigned short;
using u32 = unsigned int;
typedef __attribute__((ext_vector_type(8)))  short  short8;   // 8 bf16 (4 VGPRs) MFMA frag
typedef __attribute__((ext_vector_type(8)))  u16    ushort8;
typedef __attribute__((ext_vector_type(4)))  u16    us4;
typedef __attribute__((ext_vector_type(4)))  float  f32x4;
typedef __attribute__((ext_vector_type(16))) float  f32x16;

// ---------- problem constants ----------
constexpr int BB = 4;          // batch
constexpr int TT = 2048;       // seq len
constexpr int CC = 1024;       // embed dim
constexpr int HH = 16;         // heads
constexpr int DD = 64;         // head dim
constexpr int MM = BB * TT;    // 8192 rows
constexpr int N1 = 3 * CC;     // 3072 (qkv)

// fp32 -> bf16 round-to-nearest-even
DEV u16 f2bf(float f) {
    unsigned u = __float_as_uint(f);
    unsigned r = (u + 0x7FFFu + ((u >> 16) & 1u)) >> 16;
    return (u16)r;
}

DEV u32 cvtpk(float lo, float hi) {
    u32 r;
    asm("v_cvt_pk_bf16_f32 %0, %1, %2" : "=v"(r) : "v"(lo), "v"(hi));
    return r;
}

DEV void gload_lds16(const void* g, void* l) {
    __builtin_amdgcn_global_load_lds((const __attribute__((address_space(1))) void*)g,
                                     (__attribute__((address_space(3))) void*)l,
                                     16, 0, 0);
}

// ---------- converters ----------
__global__ void k_cvt_x(const float* __restrict__ src, u16* __restrict__ dst) {
    int i = (blockIdx.x * 256 + threadIdx.x) * 8;
    f32x4 a = *(const f32x4*)(src + i);
    f32x4 b = *(const f32x4*)(src + i + 4);
    ushort8 u;
    u[0] = f2bf(a[0]); u[1] = f2bf(a[1]); u[2] = f2bf(a[2]); u[3] = f2bf(a[3]);
    u[4] = f2bf(b[0]); u[5] = f2bf(b[1]); u[6] = f2bf(b[2]); u[7] = f2bf(b[3]);
    *(ushort8*)(dst + i) = u;
}

// LDS-tiled coalesced transpose+convert: dst[n][k] = bf16(src[k][n])
__global__ __launch_bounds__(256) void k_transpose_cvt2(const float* __restrict__ src,
                                                        u16* __restrict__ dst,
                                                        int Kd, int Nd) {
    __shared__ u16 tile[64][66];
    const int t = threadIdx.x;
    const int k0 = blockIdx.y * 64, n0 = blockIdx.x * 64;
    const int c = t & 63, r0 = (t >> 6) * 16;
#pragma unroll
    for (int i = 0; i < 16; ++i)
        tile[r0 + i][c] = f2bf(src[(size_t)(k0 + r0 + i) * Nd + n0 + c]);
    __syncthreads();
    const int kc = (t & 7) * 8, nn = t >> 3;   // nn in 0..31
#pragma unroll
    for (int h = 0; h < 2; ++h) {
        int n = nn + h * 32;
        ushort8 v;
#pragma unroll
        for (int j = 0; j < 8; ++j) v[j] = tile[kc + j][n];
        *(ushort8*)(dst + (size_t)(n0 + n) * Kd + k0 + kc) = v;
    }
}

// ---------- 128x128 GEMM mainloop, BK=64, dbuf, XOR-swizzled LDS ----------
// LDS tile: [128 rows][64 u16] = 1024 16B-chunks; phys slot p of row r holds
// global chunk p^(r&7) (linear LDS dest for global_load_lds; swizzle applied
// to the GLOBAL source address — rule 21 both-sides-or-neither).
DEV void stage_tile64(const u16* __restrict__ Ag, const u16* __restrict__ Bg, int kt,
                      u16* As, u16* Bs, int lane, int wid) {
#pragma unroll
    for (int p = 0; p < 4; ++p) {
        int cb = p * 256 + wid * 64;             // wave-uniform chunk base, covers 0..1023
        int c = cb + lane;
        int row = c >> 3, slot = c & 7;
        int g = slot ^ (row & 7);                 // global 16B-chunk for this phys slot
        gload_lds16(Ag + (size_t)row * 1024 + kt + g * 8, As + cb * 8);
        gload_lds16(Bg + (size_t)row * 1024 + kt + g * 8, Bs + cb * 8);
    }
}

DEV void gemm_ml4(const u16* __restrict__ Ag, const u16* __restrict__ Bg,
                  u16 (*As)[8192], u16 (*Bs)[8192], f32x4 acc[4][4]) {
    const int tid = threadIdx.x, lane = tid & 63, wid = tid >> 6;
    const int wr = wid >> 1, wc = wid & 1;
    stage_tile64(Ag, Bg, 0, As[0], Bs[0], lane, wid);
    asm volatile("s_waitcnt vmcnt(0)" ::: "memory");
    int cur = 0;
#pragma unroll 1
    for (int t = 0; t < 16; ++t) {
        __builtin_amdgcn_s_barrier();             // tile t staged (all waves), buf^1 free
        __builtin_amdgcn_sched_barrier(0);
        if (t + 1 < 16)                           // issue-early: flies under the 32 MFMAs
            stage_tile64(Ag, Bg, (t + 1) * 64, As[cur ^ 1], Bs[cur ^ 1], lane, wid);
#pragma unroll
        for (int kh = 0; kh < 2; ++kh) {
            const int g = kh * 4 + (lane >> 4);
            short8 aF[4], bF[4];
#pragma unroll
            for (int m = 0; m < 4; ++m) {
                int row = wr * 64 + m * 16 + (lane & 15);
                aF[m] = *(const short8*)&As[cur][row * 64 + ((g ^ (row & 7)) * 8)];
            }
#pragma unroll
            for (int n = 0; n < 4; ++n) {
                int row = wc * 64 + n * 16 + (lane & 15);
                bF[n] = *(const short8*)&Bs[cur][row * 64 + ((g ^ (row & 7)) * 8)];
            }
            __builtin_amdgcn_s_setprio(1);
#pragma unroll
            for (int m = 0; m < 4; ++m)
#pragma unroll
                for (int n = 0; n < 4; ++n)
                    acc[m][n] = __builtin_amdgcn_mfma_f32_16x16x32_bf16(aF[m], bF[n], acc[m][n], 0, 0, 0);
            __builtin_amdgcn_s_setprio(0);
        }
        asm volatile("s_waitcnt vmcnt(0)" ::: "memory");  // wait-late: t+1 landed
        __builtin_amdgcn_sched_barrier(0);
        cur ^= 1;
    }
}

// GEMM1: qkv = x @ W_qkv + b; scatter q (x0.125), k row-major, v TRANSPOSED [bh][d][t]
__global__ __launch_bounds__(256) void k_gemm_qkv(const u16* __restrict__ xb,
                                                  const u16* __restrict__ wt,
                                                  const float* __restrict__ bqkv,
                                                  u16* __restrict__ qb,
                                                  u16* __restrict__ kb,
                                                  u16* __restrict__ vtb) {
    __shared__ u16 As[2][8192], Bs[2][8192];
    f32x4 acc[4][4];
#pragma unroll
    for (int m = 0; m < 4; ++m)
#pragma unroll
        for (int n = 0; n < 4; ++n) acc[m][n] = (f32x4){0.f, 0.f, 0.f, 0.f};
    // natural order: all XCDs sweep M together per N-panel; L3 absorbs x re-reads
    const int rowBase = blockIdx.x * 128, colBase = blockIdx.y * 128;
    gemm_ml4(xb + (size_t)rowBase * 1024, wt + (size_t)colBase * 1024, As, Bs, acc);
    const int lane = threadIdx.x & 63, wid = threadIdx.x >> 6;
    const int wr = wid >> 1, wc = wid & 1;
#pragma unroll
    for (int n = 0; n < 4; ++n) {
        int gn = colBase + wc * 64 + n * 16 + (lane & 15);
        float bias = bqkv[gn];
        int which = gn >> 10, cc = gn & 1023, hh = cc >> 6, d = cc & 63;   // wave-uniform which
        if (which == 2) {
            u16* vdst = vtb + ((size_t)hh * DD + d) * TT;
#pragma unroll
            for (int m = 0; m < 4; ++m) {
                int gm = rowBase + wr * 64 + m * 16 + (lane >> 4) * 4;
                int b = gm >> 11, t = gm & 2047;
                us4 pv;
#pragma unroll
                for (int r = 0; r < 4; ++r) pv[r] = f2bf(acc[m][n][r] + bias);
                *(us4*)(vdst + (size_t)b * (HH * DD * TT) + t) = pv;
            }
        } else {
            u16* dst = (which == 0 ? qb : kb);
            float sc = (which == 0) ? 0.125f : 1.0f;
#pragma unroll
            for (int m = 0; m < 4; ++m) {
#pragma unroll
                for (int r = 0; r < 4; ++r) {
                    int gm = rowBase + wr * 64 + m * 16 + (lane >> 4) * 4 + r;
                    int b = gm >> 11, t = gm & 2047;
                    dst[(((size_t)b * HH + hh) * TT + t) * DD + d] = f2bf((acc[m][n][r] + bias) * sc);
                }
            }
        }
    }
}

// GEMM2: out = o @ W_proj + b; fp32 output
__global__ __launch_bounds__(256) void k_gemm_proj(const u16* __restrict__ ob,
                                                   const u16* __restrict__ wt,
                                                   const float* __restrict__ bproj,
                                                   float* __restrict__ out) {
    __shared__ u16 As[2][8192], Bs[2][8192];
    f32x4 acc[4][4];
#pragma unroll
    for (int m = 0; m < 4; ++m)
#pragma unroll
        for (int n = 0; n < 4; ++n) acc[m][n] = (f32x4){0.f, 0.f, 0.f, 0.f};
    const int rowBase = blockIdx.x * 128, colBase = blockIdx.y * 128;
    gemm_ml4(ob + (size_t)rowBase * 1024, wt + (size_t)colBase * 1024, As, Bs, acc);
    const int lane = threadIdx.x & 63, wid = threadIdx.x >> 6;
    const int wr = wid >> 1, wc = wid & 1;
#pragma unroll
    for (int n = 0; n < 4; ++n) {
        int gn = colBase + wc * 64 + n * 16 + (lane & 15);
        float bias = bproj[gn];
#pragma unroll
        for (int m = 0; m < 4; ++m) {
#pragma unroll
            for (int r = 0; r < 4; ++r) {
                int gm = rowBase + wr * 64 + m * 16 + (lane >> 4) * 4 + r;
                out[(size_t)gm * 1024 + gn] = acc[m][n][r] + bias;
            }
        }
    }
}

// ---------- causal flash attention: 8 warps x 32 q-rows (QBLK=256), KVBLK=64 ----------
// q,k: [bh][t][64] bf16 (q pre-scaled by 0.125). vt: [bh][64][t] bf16. o: [B*T][C] bf16.
DEV void attn_stage(const u16* __restrict__ kb_hb, const u16* __restrict__ vtb_hb,
                    int j, u16* Kd, u16* Vd, int tid) {
    int row = tid >> 3, sw = (tid & 7) ^ (row & 7);
    int cb8 = (tid & ~63) * 8;                        // wave-uniform LDS chunk base (u16 idx)
    gload_lds16(kb_hb + (size_t)(j * 64 + row) * DD + sw * 8, Kd + cb8);
    gload_lds16(vtb_hb + (size_t)row * TT + j * 64 + sw * 8,  Vd + cb8);
}

__global__ __launch_bounds__(512) void k_attn2(const u16* __restrict__ qb,
                                               const u16* __restrict__ kb,
                                               const u16* __restrict__ vtb,
                                               u16* __restrict__ ob) {
    __shared__ u16 Kt[3][4096];   // [key 64][d 64], 16B-chunk XOR-swizzled
    __shared__ u16 Vs[3][4096];   // [d 64][key 64], 16B-chunk XOR-swizzled

    const int tid = threadIdx.x, lane = tid & 63, w = tid >> 6;
    const int h = lane >> 5, l31 = lane & 31;
    const int bh = blockIdx.x;
    const int qi = 7 - blockIdx.y;            // heavy blocks dispatched first
    const size_t hb = (size_t)bh * (TT * DD);
    const int qw = qi * 256 + w * 32;         // warp's first q row
    const int nt_blk = 4 * qi + 4;            // KV tiles for the block (>=4)
    const int nt_w = (qw >> 6) + 1;           // KV tiles this warp computes
    const u16* kb_hb = kb + hb;
    const u16* vtb_hb = vtb + hb;

    // Q B-frags: col q = qw + l31, k(d) = df*16 + h*8 + j
    short8 qf[4];
#pragma unroll
    for (int df = 0; df < 4; ++df)
        qf[df] = *(const short8*)(qb + hb + (size_t)(qw + l31) * DD + df * 16 + h * 8);

    f32x16 o0, o1;
#pragma unroll
    for (int r = 0; r < 16; ++r) { o0[r] = 0.f; o1[r] = 0.f; }
    float mrun = -1e30f, lrun = 0.f;

    attn_stage(kb_hb, vtb_hb, 0, Kt[0], Vs[0], tid);
    attn_stage(kb_hb, vtb_hb, 1, Kt[1], Vs[1], tid);

    int cur = 0;
    for (int j = 0; j < nt_blk; ++j) {
        // own tile-j loads (oldest 2) landed; tile j+1's 2 may stay in flight
        if (j == nt_blk - 1) asm volatile("s_waitcnt vmcnt(0)" ::: "memory");
        else                 asm volatile("s_waitcnt vmcnt(2)" ::: "memory");
        __builtin_amdgcn_s_barrier();
        if (j + 2 < nt_blk) {
            int nb = cur + 2; if (nb > 2) nb -= 3;
            attn_stage(kb_hb, vtb_hb, j + 2, Kt[nb], Vs[nb], tid);
        }
        if (j < nt_w) {
            // ---- S^T = K Q^T : per lane one q-column (q = qw+l31), 64 key-rows ----
            f32x16 s0, s1;
#pragma unroll
            for (int r = 0; r < 16; ++r) { s0[r] = 0.f; s1[r] = 0.f; }
            __builtin_amdgcn_s_setprio(1);
#pragma unroll
            for (int df = 0; df < 4; ++df) {
                int colsw = df * 2 + h;
                int sw = (colsw ^ (l31 & 7)) * 8;
                short8 k0 = *(const short8*)&Kt[cur][l31 * 64 + sw];
                short8 k1 = *(const short8*)&Kt[cur][(l31 + 32) * 64 + sw];
                s0 = __builtin_amdgcn_mfma_f32_32x32x16_bf16(k0, qf[df], s0, 0, 0, 0);
                s1 = __builtin_amdgcn_mfma_f32_32x32x16_bf16(k1, qf[df], s1, 0, 0, 0);
            }
            __builtin_amdgcn_s_setprio(0);

            // ---- causal mask (only the warp's diagonal tile) ----
            if (j == nt_w - 1) {
                int qrel = qw + l31 - j * 64;
#pragma unroll
                for (int r = 0; r < 16; ++r) {
                    int kk = (r & 3) + 8 * (r >> 2) + 4 * h;
                    if (kk      > qrel) s0[r] = -1e30f;
                    if (kk + 32 > qrel) s1[r] = -1e30f;
                }
            }

            // ---- online softmax, defer-max (THR=8) ----
            float pm = -1e30f;
#pragma unroll
            for (int r = 0; r < 16; ++r) pm = fmaxf(pm, fmaxf(s0[r], s1[r]));
            pm = fmaxf(pm, __shfl_xor(pm, 32));
            if (!__all(pm <= mrun + 8.f)) {
                float mnew = fmaxf(mrun, pm);
                float sc = __expf(mrun - mnew);
                mrun = mnew;
                lrun *= sc;
#pragma unroll
                for (int r = 0; r < 16; ++r) {   // rare: broadcast softmax-layout -> C-layout
                    float scr = __shfl(sc, (r & 3) + 8 * (r >> 2) + 4 * h);
                    o0[r] *= scr; o1[r] *= scr;
                }
            }
            float sum = 0.f;
#pragma unroll
            for (int r = 0; r < 16; ++r) {
                float p0 = __expf(s0[r] - mrun); s0[r] = p0; sum += p0;
                float p1 = __expf(s1[r] - mrun); s1[r] = p1; sum += p1;
            }
            sum += __shfl_xor(sum, 32);
            lrun += sum;

            // ---- pack P -> bf16 A-frags (16 cvt_pk + 8 shfl) and PV ----
            __builtin_amdgcn_s_setprio(1);
#pragma unroll
            for (int f = 0; f < 4; ++f) {
                const f32x16& P = (f >= 2) ? s1 : s0;
                u32 A0, A1, B0, B1;
                if (f & 1) { A0 = cvtpk(P[8],  P[9]);  A1 = cvtpk(P[10], P[11]);
                             B0 = cvtpk(P[12], P[13]); B1 = cvtpk(P[14], P[15]); }
                else       { A0 = cvtpk(P[0],  P[1]);  A1 = cvtpk(P[2],  P[3]);
                             B0 = cvtpk(P[4],  P[5]);  B1 = cvtpk(P[6],  P[7]);  }
                u32 U0 = h ? B0 : A0, U1 = h ? B1 : A1;   // own half's words
                u32 V0 = h ? A0 : B0, V1 = h ? A1 : B1;   // export to partner half
                u32 W0 = (u32)__shfl_xor((int)V0, 32);
                u32 W1 = (u32)__shfl_xor((int)V1, 32);
                union { u32 u[4]; short8 s; } pa;
                pa.u[0] = h ? W0 : U0; pa.u[1] = h ? W1 : U1;
                pa.u[2] = h ? U0 : W0; pa.u[3] = h ? U1 : W1;
#pragma unroll
                for (int dt = 0; dt < 2; ++dt) {
                    int row = dt * 32 + l31;
                    short8 vf = *(const short8*)&Vs[cur][row * 64 + (((f * 2 + h) ^ (row & 7)) * 8)];
                    if (dt == 0) o0 = __builtin_amdgcn_mfma_f32_32x32x16_bf16(pa.s, vf, o0, 0, 0, 0);
                    else         o1 = __builtin_amdgcn_mfma_f32_32x32x16_bf16(pa.s, vf, o1, 0, 0, 0);
                }
            }
            __builtin_amdgcn_s_setprio(0);
        }
        cur = (cur == 2) ? 0 : cur + 1;
    }

    // ---- epilogue: O /= l, write [B*T][C] bf16 ----
    const int b = bh >> 4, head = bh & 15;
    float linv = 1.f / lrun;
#pragma unroll
    for (int r = 0; r < 16; ++r) {
        float li = __shfl(linv, (r & 3) + 8 * (r >> 2) + 4 * h);
        int q = qw + (r & 3) + 8 * (r >> 2) + 4 * h;
        size_t rb = ((size_t)(b * TT + q)) * CC + head * 64;
        ob[rb + l31]      = f2bf(o0[r] * li);
        ob[rb + 32 + l31] = f2bf(o1[r] * li);
    }
}

// ---------- launch ----------
extern "C" void kernel_launch(void* const* d_in, const int* in_sizes, int n_in,
                              void* d_out, int out_size, void* d_ws, size_t ws_size,
                              hipStream_t stream) {
    const float* x     = (const float*)d_in[0];
    const float* Wqkv  = (const float*)d_in[1];
    const float* bqkv  = (const float*)d_in[2];
    const float* Wproj = (const float*)d_in[3];
    const float* bproj = (const float*)d_in[4];
    float* out = (float*)d_out;

    char* ws = (char*)d_ws;
    u16* xb    = (u16*)(ws + 0);          // 16 MB (reused as ob after GEMM1)
    u16* wqkvT = (u16*)(ws + 16777216);   //  6 MB
    u16* wprojT= (u16*)(ws + 23068672);   //  2 MB
    u16* qb    = (u16*)(ws + 25165824);   // 16 MB
    u16* kb    = (u16*)(ws + 41943040);   // 16 MB
    u16* vtb   = (u16*)(ws + 58720256);   // 16 MB  [bh][d][t]
    u16* ob    = xb;                      // alias: x dead after GEMM1

    k_cvt_x<<<dim3(MM * CC / (256 * 8)), 256, 0, stream>>>(x, xb);
    k_transpose_cvt2<<<dim3(N1 / 64, CC / 64), 256, 0, stream>>>(Wqkv, wqkvT, CC, N1);
    k_transpose_cvt2<<<dim3(CC / 64, CC / 64), 256, 0, stream>>>(Wproj, wprojT, CC, CC);
    k_gemm_qkv<<<dim3(MM / 128, N1 / 128), 256, 0, stream>>>(xb, wqkvT, bqkv, qb, kb, vtb);
    k_attn2<<<dim3(BB * HH, TT / 256), 512, 0, stream>>>(qb, kb, vtb, ob);
    k_gemm_proj<<<dim3(MM / 128, CC / 128), 256, 0, stream>>>(ob, wprojT, bproj, out);
}